// Round 3
// baseline (771.805 us; speedup 1.0000x reference)
//
#include <hip/hip_runtime.h>

// R3 = CALIBRATION PROBE. R2 kernel + a second, keep-alive-only sweep over the
// weight tile of block (b ^ 2048) -> exactly 2x weight HBM traffic, same math.
// Purpose: measure the encoder's effective streaming BW via the dur_us delta.
//   delta ~ +90us  -> encoder already at ~6 TB/s roofline (harness dominates dur_us)
//   delta ~ +330us -> encoder streams at ~1.6 TB/s; doubled kernel will surface
//                     in rocprof top-5 and expose its counters.

constexpr int FEAT  = 128;
constexpr int EMBED = 128;
constexpr int NSAMP = 10;
constexpr int TWOF  = 2 * FEAT;

typedef float v4f __attribute__((ext_vector_type(4)));

__global__ __launch_bounds__(512) void encoder_kernel(
    const float* __restrict__ features,
    const float* __restrict__ weight,
    const int*   __restrict__ nodes,
    const int*   __restrict__ neigh_idx,
    float*       __restrict__ out,
    const int    batch)
{
    const int b    = blockIdx.x;
    const int t    = threadIdx.x;
    const int quad = t & 31;   // output quad: 4 consecutive embed cols
    const int seg  = t >> 5;   // row segment 0..15: rows seg*16 .. seg*16+15

    __shared__ float c[TWOF];             // combined input vector
    __shared__ float partial[16 * 128];   // [seg][embed] 8 KB

    // ---- Issue gather loads first ----
    float g;
    float r[NSAMP];
    const bool isSelf  = (t < FEAT);
    const bool isNeigh = (t >= FEAT) && (t < TWOF);
    if (isSelf) {
        g = features[(size_t)nodes[b] * FEAT + t];
    }
    if (isNeigh) {
        const int f = t - FEAT;
#pragma unroll
        for (int k = 0; k < NSAMP; ++k)
            r[k] = features[(size_t)neigh_idx[b * NSAMP + k] * FEAT + f];
    }

    const v4f* __restrict__ wtile =
        (const v4f*)(weight + (size_t)b * TWOF * EMBED)
        + (size_t)seg * 16 * 32 + quad;

    // ---- Prefetch chunk 0 across the barrier ----
    v4f w[8];
#pragma unroll
    for (int j = 0; j < 8; ++j)
        w[j] = wtile[j * 32];

    if (isSelf) {
        c[t] = g;
    }
    if (isNeigh) {
        float s = 0.f;
#pragma unroll
        for (int k = 0; k < NSAMP; ++k) s += r[k];
        c[t] = s * (1.0f / NSAMP);
    }
    __syncthreads();

    v4f wn[8];
#pragma unroll
    for (int j = 0; j < 8; ++j)
        wn[j] = wtile[(8 + j) * 32];

    float accx = 0.f, accy = 0.f, accz = 0.f, accw = 0.f;
    const int rbase = seg * 16;
#pragma unroll
    for (int j = 0; j < 8; ++j) {
        const float ci = c[rbase + j];
        accx = fmaf(ci, w[j].x, accx);
        accy = fmaf(ci, w[j].y, accy);
        accz = fmaf(ci, w[j].z, accz);
        accw = fmaf(ci, w[j].w, accw);
    }
#pragma unroll
    for (int j = 0; j < 8; ++j) {
        const float ci = c[rbase + 8 + j];
        accx = fmaf(ci, wn[j].x, accx);
        accy = fmaf(ci, wn[j].y, accy);
        accz = fmaf(ci, wn[j].z, accz);
        accw = fmaf(ci, wn[j].w, accw);
    }

    float* p = &partial[seg * 128 + quad * 4];
    p[0] = accx; p[1] = accy; p[2] = accz; p[3] = accw;
    __syncthreads();

    if (t < EMBED) {
        float s = 0.f;
#pragma unroll
        for (int sgi = 0; sgi < 16; ++sgi)
            s += partial[sgi * 128 + t];
        out[(size_t)b * EMBED + t] = fmaxf(s, 0.f);
    }

    // ---- CALIBRATION SWEEP: stream the weight tile of block (b ^ 2048) ----
    // Bijective over grid -> every weight byte read exactly twice in total.
    // 256 MiB away -> cannot be served by the 256 MiB L3 given the 1 GiB stream.
    // Keep-alive via asm so it cannot be DCE'd (rule: ablation-via-skip DCEs).
    {
        const int b2 = (b ^ 2048) < batch ? (b ^ 2048) : b;
        const v4f* __restrict__ wtile2 =
            (const v4f*)(weight + (size_t)b2 * TWOF * EMBED)
            + (size_t)seg * 16 * 32 + quad;
        v4f acc2 = {0.f, 0.f, 0.f, 0.f};
#pragma unroll
        for (int half = 0; half < 2; ++half) {
            v4f w2[8];
#pragma unroll
            for (int j = 0; j < 8; ++j)
                w2[j] = wtile2[(half * 8 + j) * 32];
#pragma unroll
            for (int j = 0; j < 8; ++j)
                acc2 += w2[j];
        }
        asm volatile("" :: "v"(acc2.x), "v"(acc2.y), "v"(acc2.z), "v"(acc2.w));
    }
}

extern "C" void kernel_launch(void* const* d_in, const int* in_sizes, int n_in,
                              void* d_out, int out_size, void* d_ws, size_t ws_size,
                              hipStream_t stream) {
    const float* features = (const float*)d_in[0];   // [100000,128] f32
    const float* weight   = (const float*)d_in[1];   // [4096,256,128] f32
    const int*   nodes    = (const int*)d_in[2];     // [4096] i32
    const int*   neigh    = (const int*)d_in[3];     // [4096,10] i32
    float*       outp     = (float*)d_out;           // [4096,128] f32

    const int batch = in_sizes[2];  // 4096
    encoder_kernel<<<batch, 512, 0, stream>>>(features, weight, nodes, neigh, outp, batch);
}

// Round 4
// 688.475 us; speedup vs baseline: 1.1210x; 1.1210x over previous
//
#include <hip/hip_runtime.h>

// B=4096, F=128, E=128, NS=10
//   out[b] = relu(concat(features[nodes[b]], mean_k features[neigh_idx[b,k]]) @ weight[b])
//
// FINAL (R4 = R2 reverted from the R3 calibration probe).
// Roofline evidence (R3): adding exactly +512 MiB of weight streaming to this
// kernel cost +83 us -> effective stream BW 6.5 TB/s = achievable HBM ceiling.
// Mandatory traffic: 537 MB weight (read once) + ~23 MB gathers + 2 MB out
// => ~90 us floor; the encoder is within a few percent of it. The rest of the
// harness dur_us (~580 us) is fixed work (2 GiB poison fill ~335 us + restores),
// invariant across all kernel structures tried (676/686/689 us).
//
// Structure: 1 block/item, 512 threads (8 waves). Thread t owns output quad
// (t&31), rows seg*16..seg*16+15 (seg=t>>5). Gather loads issued before the
// weight prefetch; chunk-1 loads fly under chunk-0 FMAs; 8 KB LDS reduction.

constexpr int FEAT  = 128;
constexpr int EMBED = 128;
constexpr int NSAMP = 10;
constexpr int TWOF  = 2 * FEAT;

typedef float v4f __attribute__((ext_vector_type(4)));

__global__ __launch_bounds__(512) void encoder_kernel(
    const float* __restrict__ features,
    const float* __restrict__ weight,
    const int*   __restrict__ nodes,
    const int*   __restrict__ neigh_idx,
    float*       __restrict__ out)
{
    const int b    = blockIdx.x;
    const int t    = threadIdx.x;
    const int quad = t & 31;   // output quad: 4 consecutive embed cols
    const int seg  = t >> 5;   // row segment 0..15: rows seg*16 .. seg*16+15

    __shared__ float c[TWOF];             // combined input vector
    __shared__ float partial[16 * 128];   // [seg][embed] 8 KB

    // ---- Issue gather loads first (long latency, critical path to the sync) ----
    float g;
    float r[NSAMP];
    const bool isSelf  = (t < FEAT);
    const bool isNeigh = (t >= FEAT) && (t < TWOF);
    if (isSelf) {
        g = features[(size_t)nodes[b] * FEAT + t];
    }
    if (isNeigh) {
        const int f = t - FEAT;
#pragma unroll
        for (int k = 0; k < NSAMP; ++k)
            r[k] = features[(size_t)neigh_idx[b * NSAMP + k] * FEAT + f];
    }

    // ---- Weight tile pointer: rows seg*16..+15, cols quad*4..+3 ----
    const v4f* __restrict__ wtile =
        (const v4f*)(weight + (size_t)b * TWOF * EMBED)
        + (size_t)seg * 16 * 32 + quad;

    // ---- Prefetch chunk 0 (rows 0..7 of this thread's 16) across the barrier ----
    v4f w[8];
#pragma unroll
    for (int j = 0; j < 8; ++j)
        w[j] = wtile[j * 32];

    // ---- Finish gather, publish c, sync ----
    if (isSelf) {
        c[t] = g;
    }
    if (isNeigh) {
        float s = 0.f;
#pragma unroll
        for (int k = 0; k < NSAMP; ++k) s += r[k];
        c[t] = s * (1.0f / NSAMP);
    }
    __syncthreads();

    // ---- Chunk 1 loads fly while chunk 0 FMAs run ----
    v4f wn[8];
#pragma unroll
    for (int j = 0; j < 8; ++j)
        wn[j] = wtile[(8 + j) * 32];

    float accx = 0.f, accy = 0.f, accz = 0.f, accw = 0.f;
    const int rbase = seg * 16;
#pragma unroll
    for (int j = 0; j < 8; ++j) {
        const float ci = c[rbase + j];
        accx = fmaf(ci, w[j].x, accx);
        accy = fmaf(ci, w[j].y, accy);
        accz = fmaf(ci, w[j].z, accz);
        accw = fmaf(ci, w[j].w, accw);
    }
#pragma unroll
    for (int j = 0; j < 8; ++j) {
        const float ci = c[rbase + 8 + j];
        accx = fmaf(ci, wn[j].x, accx);
        accy = fmaf(ci, wn[j].y, accy);
        accz = fmaf(ci, wn[j].z, accz);
        accw = fmaf(ci, wn[j].w, accw);
    }

    // partial[seg][quad*4 + 0..3]
    float* p = &partial[seg * 128 + quad * 4];
    p[0] = accx; p[1] = accy; p[2] = accz; p[3] = accw;
    __syncthreads();

    // ---- Reduce 16 segments per output element, ReLU, coalesced store ----
    if (t < EMBED) {
        float s = 0.f;
#pragma unroll
        for (int sgi = 0; sgi < 16; ++sgi)
            s += partial[sgi * 128 + t];
        out[(size_t)b * EMBED + t] = fmaxf(s, 0.f);
    }
}

extern "C" void kernel_launch(void* const* d_in, const int* in_sizes, int n_in,
                              void* d_out, int out_size, void* d_ws, size_t ws_size,
                              hipStream_t stream) {
    const float* features = (const float*)d_in[0];   // [100000,128] f32
    const float* weight   = (const float*)d_in[1];   // [4096,256,128] f32
    const int*   nodes    = (const int*)d_in[2];     // [4096] i32
    const int*   neigh    = (const int*)d_in[3];     // [4096,10] i32
    float*       outp     = (float*)d_out;           // [4096,128] f32

    const int batch = in_sizes[2];  // 4096
    encoder_kernel<<<batch, 512, 0, stream>>>(features, weight, nodes, neigh, outp);
}